// Round 4
// baseline (1237.869 us; speedup 1.0000x reference)
//
#include <hip/hip_runtime.h>
#include <stdint.h>
#include <stddef.h>

// ---------------------------------------------------------------------------
// AddInterpolant: xt/dt_xt of a 4-layer MLP flow interpolant, B=65536.
//   z=[x0|x1|t] (513)->1024->1024->1024->256, relu between; JVP wrt t-slot.
//   Tangent into layer1 is r1 = W1[512,:] (sample-independent).
//
// History:
//  R1/R2: launch_bounds(256,3) spilled the dual accumulators (WRITE 706MB);
//         band-preserving XCD swizzle halves FETCH (528->105MB). 1107us @ R3,
//         mid GEMM 790 TF, MfmaUtil 33% = the 2-barrier vmcnt(0)-drain
//         structural ceiling (~900TF class). HBM at 17% -> traffic done.
//  R4: structural rewrite to the 256^2 8-phase counted-vmcnt schedule.
//   * [H;U] STACKED operand: H-rows and U-rows of the same 16-sample group
//     interleaved at 16-row granularity in one [2CB,1024] matrix. Both GEMMs
//     share W -> ONE accumulator set (128 VGPR); even mi = H frag, odd mi =
//     U frag of the SAME samples in the SAME lanes -> relu-mask epilogue
//     stays lane-local. Layer1 (M=CB) writes the stacked buffer (U = mask*r1).
//   * 8 waves (2Mx4N), BM=BN=256, BK=64, LDS 128KiB double-buffered.
//   * tile t+1 loads issued at top of iter t (buffer t-1 retired by the
//     final phase barrier of iter t-1) -> full-iteration latency cover;
//     boundary wait vmcnt(8) = "tile t done, tile t+1 stays in flight".
//   * 4 phases/K-tile: {12 ds_read_b128; barrier; lgkmcnt(0); setprio(1);
//     16 MFMA; setprio(0); barrier}. Proven XOR k-chunk swizzle kept
//     (global-side pre-swizzle, linear LDS dest; bank-conflict 0 in R0-R3).
//   * band-preserving XCD swizzle kept (FETCH lever, verified R3).
// ---------------------------------------------------------------------------

typedef unsigned short u16;
typedef __attribute__((ext_vector_type(8))) short short8;
typedef __attribute__((ext_vector_type(4))) float f32x4;

#define BATCH 65536
#define SDIM 256
#define HDIM 1024

__device__ __forceinline__ u16 f2bf(float f) {
  unsigned int u = __float_as_uint(f);
  u += 0x7FFFu + ((u >> 16) & 1u);   // round-to-nearest-even
  return (u16)(u >> 16);
}

__device__ __forceinline__ void gload_lds16(const void* g, void* l) {
  // 16B/lane; LDS dest = wave-uniform base + lane*16 (hardware rule).
  __builtin_amdgcn_global_load_lds(
      (const __attribute__((address_space(1))) unsigned int*)g,
      (__attribute__((address_space(3))) unsigned int*)l, 16, 0, 0);
}

struct EpiArgs {
  const float* bias;
  const float* r1;    // W1 row 512 (f32)
  const float* t;     // chunk-local base
  const float* x0;
  const float* x1;
  u16*   out_h;       // stacked S output (EPI 0/1)
  float* out_xt;
  float* out_dt;
};

// C = A[M,64-tiled K] @ Bt[N,K]^T, bf16 in, f32 acc. BM=BN=256, BK=64,
// 512 threads = 8 waves (2M x 4N), per-wave C = 128x64 = acc[8][4] f32x4.
// EPI 0: layer1. A=Z [CB,512] plain; pre=acc+b[n]+t[m]*r1[n];
//        stacked out: H row sH, U row sH+16 (U = mask*r1).
// EPI 1: mid. A=S stacked; even/odd mi pairs -> (pre, vu);
//        H'=relu(pre), U'=mask*vu, written stacked.
// EPI 2: layer4+combine. fnn/dtfnn pairs -> xt, dt_xt (f32).
template <int EPI>
__global__ __launch_bounds__(512, 2)
void fgemm8(const u16* __restrict__ A, const u16* __restrict__ Bt,
            int N, int K, EpiArgs e)
{
  __shared__ __align__(16) u16 lds[65536];  // 128 KiB: [2 bufs][A 16K | B 16K u16]

  const int tid  = threadIdx.x;
  const int wave = tid >> 6;
  const int lane = tid & 63;
  const int hi   = lane >> 4;   // 0..3
  const int ln   = lane & 15;
  const int srow = lane >> 3;   // row within 8-row staging chunk
  const int ssc  = lane & 7;    // 16B slot within row
  const int lcs  = (ssc ^ srow) * 8;  // global-side swizzled k-slot (u16 off)

  // Band-preserving XCD swizzle (verified R3: FETCH 528->105MB, WRITE ideal).
  const int nbx = gridDim.x;
  int bx = blockIdx.x, by = blockIdx.y;
  if ((gridDim.y & 7) == 0) {
    const int id = by * nbx + bx;
    const int g  = id & 7;
    const int s  = id >> 3;
    bx = s % nbx;
    by = (s / nbx) * 8 + g;
  }
  const int bn = bx * 256;
  const int bm = by * 256;

  const int wm = (wave >> 2) * 128;   // 2 M-wave groups
  const int wn = (wave & 3) * 64;     // 4 N-wave groups

  f32x4 acc[8][4] = {};

  const u16* gA = A  + (size_t)bm * K + lcs;
  const u16* gB = Bt + (size_t)bn * K + lcs;
  const int NT = K >> 6;              // >= 8 always

  // Stage K-tile t into buffer (t&1): 8 gload_lds per thread-wave share
  // (4 A-chunks + 4 B-chunks of 8 rows x 64 cols each).
  auto STAGE = [&](int t) {
    const int kk0 = t << 6;
    const int lb  = (t & 1) << 15;    // u16 offset 0 / 32768
#pragma unroll
    for (int c = 0; c < 4; ++c) {
      const int ch  = (wave << 2) + c;       // 0..31
      const int row = (ch << 3) + srow;      // 0..255
      gload_lds16(gA + (size_t)row * K + kk0, &lds[lb + ch * 512]);
      gload_lds16(gB + (size_t)row * K + kk0, &lds[lb + 16384 + ch * 512]);
    }
  };

  STAGE(0);
  STAGE(1);

  for (int t = 0; t < NT; ++t) {
    const int lb = (t & 1) << 15;
    // Issue tile t+1 loads NOW (buffer t-1 retired at end of iter t-1):
    // they get a full iteration of latency cover.
    if (t >= 1 && t + 1 < NT) STAGE(t + 1);
    // Counted wait: tile t's 8 loads done; tile t+1's 8 stay in flight.
    if (t + 1 < NT) asm volatile("s_waitcnt vmcnt(8)" ::: "memory");
    else            asm volatile("s_waitcnt vmcnt(0)" ::: "memory");
    __builtin_amdgcn_s_barrier();

#pragma unroll
    for (int p = 0; p < 4; ++p) {
      const int mbase = (p >> 1) * 4;   // mi quadrant: 0 / 4
      const int nbase = (p & 1) * 2;    // ni quadrant: 0 / 2
      short8 ah[4][2], bb[2][2];
#pragma unroll
      for (int i = 0; i < 4; ++i) {
        const int row = wm + (mbase + i) * 16 + ln;
#pragma unroll
        for (int kh = 0; kh < 2; ++kh) {
          const int scs = (((kh << 2) + hi) ^ (ln & 7)) * 8;  // un-swizzle
          ah[i][kh] = *(const short8*)&lds[lb + row * 64 + scs];
        }
      }
#pragma unroll
      for (int j = 0; j < 2; ++j) {
        const int row = wn + (nbase + j) * 16 + ln;
#pragma unroll
        for (int kh = 0; kh < 2; ++kh) {
          const int scs = (((kh << 2) + hi) ^ (ln & 7)) * 8;
          bb[j][kh] = *(const short8*)&lds[lb + 16384 + row * 64 + scs];
        }
      }
      __builtin_amdgcn_s_barrier();
      asm volatile("s_waitcnt lgkmcnt(0)");
      __builtin_amdgcn_s_setprio(1);
#pragma unroll
      for (int i = 0; i < 4; ++i)
#pragma unroll
        for (int j = 0; j < 2; ++j) {
          acc[mbase + i][nbase + j] = __builtin_amdgcn_mfma_f32_16x16x32_bf16(
              ah[i][0], bb[j][0], acc[mbase + i][nbase + j], 0, 0, 0);
          acc[mbase + i][nbase + j] = __builtin_amdgcn_mfma_f32_16x16x32_bf16(
              ah[i][1], bb[j][1], acc[mbase + i][nbase + j], 0, 0, 0);
        }
      __builtin_amdgcn_s_setprio(0);
      __builtin_amdgcn_s_barrier();
    }
  }

  // ---- epilogue. C/D layout: col = lane&15, row = (lane>>4)*4 + reg [m89].
  if constexpr (EPI == 0) {
    // A rows were samples. Write stacked: H -> row sH, U=mask*r1 -> sH+16.
#pragma unroll
    for (int mi = 0; mi < 8; ++mi) {
#pragma unroll
      for (int ni = 0; ni < 4; ++ni) {
        const int n = bn + wn + ni * 16 + ln;
        const float bnv = e.bias[n];
        const float r1n = e.r1[n];
#pragma unroll
        for (int r = 0; r < 4; ++r) {
          const int m = bm + wm + mi * 16 + hi * 4 + r;   // chunk-local sample
          const float pre = acc[mi][ni][r] + bnv + e.t[m] * r1n;
          const size_t sH = (size_t)(m >> 4) * 32 + (m & 15);
          e.out_h[sH * (size_t)N + n]        = f2bf(fmaxf(pre, 0.f));
          e.out_h[(sH + 16) * (size_t)N + n] = (pre > 0.f) ? f2bf(r1n) : (u16)0;
        }
      }
    }
  } else if constexpr (EPI == 1) {
    // Stacked in, stacked out: mi pairs (2j=H, 2j+1=U) of same samples.
#pragma unroll
    for (int j = 0; j < 4; ++j) {
#pragma unroll
      for (int ni = 0; ni < 4; ++ni) {
        const int n = bn + wn + ni * 16 + ln;
        const float bnv = e.bias[n];
#pragma unroll
        for (int r = 0; r < 4; ++r) {
          const size_t sH = (size_t)(bm + wm + j * 32 + hi * 4 + r);
          const float pre = acc[2 * j][ni][r] + bnv;
          const float vu  = acc[2 * j + 1][ni][r];
          e.out_h[sH * (size_t)N + n]        = f2bf(fmaxf(pre, 0.f));
          e.out_h[(sH + 16) * (size_t)N + n] = (pre > 0.f) ? f2bf(vu) : (u16)0;
        }
      }
    }
  } else {
    // Final: fnn (even mi) + dtfnn (odd mi) -> xt, dt_xt.
#pragma unroll
    for (int j = 0; j < 4; ++j) {
#pragma unroll
      for (int ni = 0; ni < 4; ++ni) {
        const int n = bn + wn + ni * 16 + ln;   // < 256
        const float bnv = e.bias[n];
#pragma unroll
        for (int r = 0; r < 4; ++r) {
          const int sH = bm + wm + j * 32 + hi * 4 + r;
          const int m  = ((sH >> 5) << 4) + (hi * 4 + r);  // chunk-local sample
          const float fnn = acc[2 * j][ni][r] + bnv;
          const float dtf = acc[2 * j + 1][ni][r];
          const float tt  = e.t[m];
          const size_t ix = (size_t)m * 256 + n;
          const float a = e.x0[ix], b = e.x1[ix];
          const float w = tt * (1.f - tt);
          e.out_xt[ix] = (1.f - tt) * a + tt * b + w * fnn;
          e.out_dt[ix] = b - a + (1.f - 2.f * tt) * fnn + w * dtf;
        }
      }
    }
  }
}

// Z = bf16([x0 | x1]) chunk, [CB, 512]; one thread per 4 elements.
__global__ void prep_z(const float* __restrict__ x0, const float* __restrict__ x1,
                       u16* __restrict__ A0)
{
  const int idx = blockIdx.x * blockDim.x + threadIdx.x;
  const int m = idx >> 7;        // 128 4-elem chunks per row
  const int c = idx & 127;
  const float* src = (c < 64) ? (x0 + (size_t)m * 256 + c * 4)
                              : (x1 + (size_t)m * 256 + (c - 64) * 4);
  const float4 v = *(const float4*)src;
  uint2 pk;
  pk.x = (unsigned)f2bf(v.x) | ((unsigned)f2bf(v.y) << 16);
  pk.y = (unsigned)f2bf(v.z) | ((unsigned)f2bf(v.w) << 16);
  *(uint2*)&A0[(size_t)m * 512 + c * 4] = pk;
}

// Wt[N,K] bf16 <- W[K,N] f32, 32x32 LDS tile transpose.
__global__ void transpose_cast(const float* __restrict__ W, u16* __restrict__ Wt,
                               int K, int N)
{
  __shared__ float tile[32][33];
  const int tx = threadIdx.x & 31;
  const int ty = threadIdx.x >> 5;  // 0..7
  const int k0 = blockIdx.x * 32;
  const int n0 = blockIdx.y * 32;
#pragma unroll
  for (int i = 0; i < 32; i += 8)
    tile[ty + i][tx] = W[(size_t)(k0 + ty + i) * N + n0 + tx];
  __syncthreads();
#pragma unroll
  for (int i = 0; i < 32; i += 8)
    Wt[(size_t)(n0 + ty + i) * K + k0 + tx] = f2bf(tile[tx][ty + i]);
}

extern "C" void kernel_launch(void* const* d_in, const int* in_sizes, int n_in,
                              void* d_out, int out_size, void* d_ws, size_t ws_size,
                              hipStream_t stream)
{
  const float* x0 = (const float*)d_in[0];
  const float* x1 = (const float*)d_in[1];
  const float* t  = (const float*)d_in[2];
  const float* W1 = (const float*)d_in[3];
  const float* b1 = (const float*)d_in[4];
  const float* W2 = (const float*)d_in[5];
  const float* b2 = (const float*)d_in[6];
  const float* W3 = (const float*)d_in[7];
  const float* b3 = (const float*)d_in[8];
  const float* W4 = (const float*)d_in[9];
  const float* b4 = (const float*)d_in[10];

  char* ws = (char*)d_ws;
  const size_t WB1 = (size_t)512 * HDIM * 2;   // 1 MiB
  const size_t WB2 = (size_t)HDIM * HDIM * 2;  // 2 MiB
  const size_t WB4 = (size_t)HDIM * SDIM * 2;  // 0.5 MiB
  u16* Wt1 = (u16*)(ws);
  u16* Wt2 = (u16*)(ws + WB1);
  u16* Wt3 = (u16*)(ws + WB1 + WB2);
  u16* Wt4 = (u16*)(ws + WB1 + 2 * WB2);
  const size_t wmark = WB1 + 2 * WB2 + WB4;    // 5.5 MiB
  char* act = ws + wmark;

  // Stacked activations: Sa, Sb = [2*CB, 1024] bf16 = CB*4096 B each.
  // Same footprint as before -> same adaptive chunking.
  int nc = 1;
  while (nc < 64 && wmark + (size_t)(BATCH / nc) * 8192 > ws_size) nc <<= 1;
  const int CB = BATCH / nc;

  u16* Sa = (u16*)(act);
  u16* Sb = (u16*)(act + (size_t)CB * 4096);
  u16* Zc = Sb;  // alias: Z chunk (CB*1024 B) dead once layer 2 writes Sb

  transpose_cast<<<dim3(16, 32), 256, 0, stream>>>(W1, Wt1, 512, HDIM);
  transpose_cast<<<dim3(32, 32), 256, 0, stream>>>(W2, Wt2, HDIM, HDIM);
  transpose_cast<<<dim3(32, 32), 256, 0, stream>>>(W3, Wt3, HDIM, HDIM);
  transpose_cast<<<dim3(32, 8),  256, 0, stream>>>(W4, Wt4, HDIM, SDIM);

  const float* r1 = W1 + (size_t)512 * HDIM;   // last row of W1
  float* out_xt = (float*)d_out;
  float* out_dt = (float*)d_out + (size_t)BATCH * SDIM;

  for (int c = 0; c < nc; ++c) {
    const size_t mb = (size_t)c * CB;

    prep_z<<<(CB * 128) / 256, 256, 0, stream>>>(x0 + mb * SDIM, x1 + mb * SDIM, Zc);

    { EpiArgs e{}; e.bias = b1; e.r1 = r1; e.t = t + mb; e.out_h = Sa;
      fgemm8<0><<<dim3(HDIM / 256, CB / 256), 512, 0, stream>>>(Zc, Wt1, HDIM, 512, e); }

    { EpiArgs e{}; e.bias = b2; e.out_h = Sb;
      fgemm8<1><<<dim3(HDIM / 256, CB / 128), 512, 0, stream>>>(Sa, Wt2, HDIM, HDIM, e); }

    { EpiArgs e{}; e.bias = b3; e.out_h = Sa;
      fgemm8<1><<<dim3(HDIM / 256, CB / 128), 512, 0, stream>>>(Sb, Wt3, HDIM, HDIM, e); }

    { EpiArgs e{}; e.bias = b4; e.t = t + mb;
      e.x0 = x0 + mb * SDIM; e.x1 = x1 + mb * SDIM;
      e.out_xt = out_xt + mb * SDIM; e.out_dt = out_dt + mb * SDIM;
      fgemm8<2><<<dim3(SDIM / 256, CB / 128), 512, 0, stream>>>(Sa, Wt4, SDIM, HDIM, e); }
  }
}

// Round 5
// 1096.389 us; speedup vs baseline: 1.1290x; 1.1290x over previous
//
#include <hip/hip_runtime.h>
#include <stdint.h>
#include <stddef.h>

// ---------------------------------------------------------------------------
// AddInterpolant: xt/dt_xt of a 4-layer MLP flow interpolant, B=65536.
//   z=[x0|x1|t] (513)->1024->1024->1024->256, relu between; JVP wrt t-slot.
//   Tangent into layer1 is r1 = W1[512,:] (sample-independent).
//
// History:
//  R3: 128^2 fused dual-acc kernel + band-preserving XCD swizzle: 1107us,
//      mid GEMM 790TF / MfmaUtil 33% = vmcnt(0)-drain structural ceiling.
//  R4: 256^2 8-phase port with [H;U]-stacked operand: REGRESSED (196us mid,
//      MfmaUtil 29%). Post-mortem: (1) quadrant phases re-read A per n-half
//      and B per m-half -> 48 ds_read_b128/wave/tile vs minimal 24 -> LDS
//      unit 2.4x the MFMA pipe; (2) lockstep {12 reads; barrier; lgkmcnt(0)}
//      serializes a 96-read LDS burst per phase before any MFMA.
//  R5: keep dbuf-LDS + counted vmcnt(8) + raw s_barrier (no implicit drain),
//      drop the per-phase lockstep: one compiler-scheduled compute block per
//      K-tile with MINIMAL reads (12 frags per kh-half, 24 total, each frag
//      feeds 32 MFMAs), 2 raw barriers/tile, sched_barrier(0) fences at the
//      edges, setprio around MFMA runs, STAGE(t+2) after the read-retire
//      barrier (full-tile latency cover; buffer hazard proven safe).
//      Compiler emits fine-grained counted lgkmcnt for ds_read->MFMA (m97
//      evidence) - that part was never the problem; the drain was.
// ---------------------------------------------------------------------------

typedef unsigned short u16;
typedef __attribute__((ext_vector_type(8))) short short8;
typedef __attribute__((ext_vector_type(4))) float f32x4;

#define BATCH 65536
#define SDIM 256
#define HDIM 1024

__device__ __forceinline__ u16 f2bf(float f) {
  unsigned int u = __float_as_uint(f);
  u += 0x7FFFu + ((u >> 16) & 1u);   // round-to-nearest-even
  return (u16)(u >> 16);
}

__device__ __forceinline__ void gload_lds16(const void* g, void* l) {
  // 16B/lane; LDS dest = wave-uniform base + lane*16 (hardware rule).
  __builtin_amdgcn_global_load_lds(
      (const __attribute__((address_space(1))) unsigned int*)g,
      (__attribute__((address_space(3))) unsigned int*)l, 16, 0, 0);
}

struct EpiArgs {
  const float* bias;
  const float* r1;    // W1 row 512 (f32)
  const float* t;     // chunk-local base
  const float* x0;
  const float* x1;
  u16*   out_h;       // stacked S output (EPI 0/1)
  float* out_xt;
  float* out_dt;
};

// C = A[M,64-tiled K] @ Bt[N,K]^T, bf16 in, f32 acc. BM=BN=256, BK=64,
// 512 threads = 8 waves (2M x 4N), per-wave C = 128x64 = acc[8][4] f32x4.
// EPI 0: layer1. A=Z [CB,512] plain; pre=acc+b[n]+t[m]*r1[n];
//        stacked out: H row sH, U row sH+16 (U = mask*r1).
// EPI 1: mid. A=S stacked; even/odd mi pairs -> (pre, vu);
//        H'=relu(pre), U'=mask*vu, written stacked.
// EPI 2: layer4+combine. fnn/dtfnn pairs -> xt, dt_xt (f32).
template <int EPI>
__global__ __launch_bounds__(512, 2)
void fgemm8(const u16* __restrict__ A, const u16* __restrict__ Bt,
            int N, int K, EpiArgs e)
{
  __shared__ __align__(16) u16 lds[65536];  // 128 KiB: [2 bufs][A 16K | B 16K u16]

  const int tid  = threadIdx.x;
  const int wave = tid >> 6;
  const int lane = tid & 63;
  const int hi   = lane >> 4;   // 0..3
  const int ln   = lane & 15;
  const int srow = lane >> 3;   // row within 8-row staging chunk
  const int ssc  = lane & 7;    // 16B slot within row
  const int lcs  = (ssc ^ srow) * 8;  // global-side swizzled k-slot (u16 off)

  // Band-preserving XCD swizzle (verified R3: FETCH 528->105MB, WRITE ideal).
  const int nbx = gridDim.x;
  int bx = blockIdx.x, by = blockIdx.y;
  if ((gridDim.y & 7) == 0) {
    const int id = by * nbx + bx;
    const int g  = id & 7;
    const int s  = id >> 3;
    bx = s % nbx;
    by = (s / nbx) * 8 + g;
  }
  const int bn = bx * 256;
  const int bm = by * 256;

  const int wm = (wave >> 2) * 128;   // 2 M-wave groups
  const int wn = (wave & 3) * 64;     // 4 N-wave groups

  f32x4 acc[8][4] = {};

  const u16* gA = A  + (size_t)bm * K + lcs;
  const u16* gB = Bt + (size_t)bn * K + lcs;
  const int NT = K >> 6;              // >= 8 always

  // Stage K-tile t into buffer (t&1): 8 gload_lds per thread
  // (4 A-chunks + 4 B-chunks of 8 rows x 64 cols each).
  auto STAGE = [&](int t) {
    const int kk0 = t << 6;
    const int lb  = (t & 1) << 15;    // u16 offset 0 / 32768
#pragma unroll
    for (int c = 0; c < 4; ++c) {
      const int ch  = (wave << 2) + c;       // 0..31
      const int row = (ch << 3) + srow;      // 0..255
      gload_lds16(gA + (size_t)row * K + kk0, &lds[lb + ch * 512]);
      gload_lds16(gB + (size_t)row * K + kk0, &lds[lb + 16384 + ch * 512]);
    }
  };

  STAGE(0);
  STAGE(1);

  for (int t = 0; t < NT; ++t) {
    // Counted wait: tile t's 8 loads done; tile t+1's 8 stay in flight.
    // STAGE(t+1) was issued at the END of iter t-1 -> full compute(t-1)... 
    // actually full barrier-to-barrier gap of cover; never drains to 0
    // mid-loop (the R3 ceiling's root cause).
    if (t + 1 < NT) asm volatile("s_waitcnt vmcnt(8)" ::: "memory");
    else            asm volatile("s_waitcnt vmcnt(0)" ::: "memory");
    __builtin_amdgcn_s_barrier();          // raw: no implicit vmcnt drain
    __builtin_amdgcn_sched_barrier(0);     // nothing crosses the barrier

    const int lb = (t & 1) << 15;
    // One compiler-scheduled block: 24 ds_read_b128 (minimal) + 64 MFMA.
    // 12 frags live per kh-half (48 VGPR); each frag feeds 4-8 MFMAs.
#pragma unroll
    for (int kh = 0; kh < 2; ++kh) {
      const int scs = (((kh << 2) + hi) ^ (ln & 7)) * 8;  // un-swizzle
      short8 a8[8], b8[4];
#pragma unroll
      for (int i = 0; i < 8; ++i)
        a8[i] = *(const short8*)&lds[lb + (wm + i * 16 + ln) * 64 + scs];
#pragma unroll
      for (int j = 0; j < 4; ++j)
        b8[j] = *(const short8*)&lds[lb + 16384 + (wn + j * 16 + ln) * 64 + scs];
      __builtin_amdgcn_s_setprio(1);
#pragma unroll
      for (int i = 0; i < 8; ++i)
#pragma unroll
        for (int j = 0; j < 4; ++j)
          acc[i][j] = __builtin_amdgcn_mfma_f32_16x16x32_bf16(
              a8[i], b8[j], acc[i][j], 0, 0, 0);
      __builtin_amdgcn_s_setprio(0);
    }

    __builtin_amdgcn_sched_barrier(0);
    __builtin_amdgcn_s_barrier();          // all waves' reads of buf t&1 done
    __builtin_amdgcn_sched_barrier(0);     // (consumed by MFMAs above)
    if (t + 2 < NT) STAGE(t + 2);          // overwrite buf t&1: now safe
  }

  // ---- epilogue. C/D layout: col = lane&15, row = (lane>>4)*4 + reg [m89].
  if constexpr (EPI == 0) {
    // A rows were samples. Write stacked: H -> row sH, U=mask*r1 -> sH+16.
#pragma unroll
    for (int mi = 0; mi < 8; ++mi) {
#pragma unroll
      for (int ni = 0; ni < 4; ++ni) {
        const int n = bn + wn + ni * 16 + ln;
        const float bnv = e.bias[n];
        const float r1n = e.r1[n];
#pragma unroll
        for (int r = 0; r < 4; ++r) {
          const int m = bm + wm + mi * 16 + hi * 4 + r;   // chunk-local sample
          const float pre = acc[mi][ni][r] + bnv + e.t[m] * r1n;
          const size_t sH = (size_t)(m >> 4) * 32 + (m & 15);
          e.out_h[sH * (size_t)N + n]        = f2bf(fmaxf(pre, 0.f));
          e.out_h[(sH + 16) * (size_t)N + n] = (pre > 0.f) ? f2bf(r1n) : (u16)0;
        }
      }
    }
  } else if constexpr (EPI == 1) {
    // Stacked in, stacked out: mi pairs (2j=H, 2j+1=U) of same samples.
#pragma unroll
    for (int j = 0; j < 4; ++j) {
#pragma unroll
      for (int ni = 0; ni < 4; ++ni) {
        const int n = bn + wn + ni * 16 + ln;
        const float bnv = e.bias[n];
#pragma unroll
        for (int r = 0; r < 4; ++r) {
          const size_t sH = (size_t)(bm + wm + j * 32 + hi * 4 + r);
          const float pre = acc[2 * j][ni][r] + bnv;
          const float vu  = acc[2 * j + 1][ni][r];
          e.out_h[sH * (size_t)N + n]        = f2bf(fmaxf(pre, 0.f));
          e.out_h[(sH + 16) * (size_t)N + n] = (pre > 0.f) ? f2bf(vu) : (u16)0;
        }
      }
    }
  } else {
    // Final: fnn (even mi) + dtfnn (odd mi) -> xt, dt_xt.
#pragma unroll
    for (int j = 0; j < 4; ++j) {
#pragma unroll
      for (int ni = 0; ni < 4; ++ni) {
        const int n = bn + wn + ni * 16 + ln;   // < 256
        const float bnv = e.bias[n];
#pragma unroll
        for (int r = 0; r < 4; ++r) {
          const int sH = bm + wm + j * 32 + hi * 4 + r;
          const int m  = ((sH >> 5) << 4) + (hi * 4 + r);  // chunk-local sample
          const float fnn = acc[2 * j][ni][r] + bnv;
          const float dtf = acc[2 * j + 1][ni][r];
          const float tt  = e.t[m];
          const size_t ix = (size_t)m * 256 + n;
          const float a = e.x0[ix], b = e.x1[ix];
          const float w = tt * (1.f - tt);
          e.out_xt[ix] = (1.f - tt) * a + tt * b + w * fnn;
          e.out_dt[ix] = b - a + (1.f - 2.f * tt) * fnn + w * dtf;
        }
      }
    }
  }
}

// Z = bf16([x0 | x1]) chunk, [CB, 512]; one thread per 4 elements.
__global__ void prep_z(const float* __restrict__ x0, const float* __restrict__ x1,
                       u16* __restrict__ A0)
{
  const int idx = blockIdx.x * blockDim.x + threadIdx.x;
  const int m = idx >> 7;        // 128 4-elem chunks per row
  const int c = idx & 127;
  const float* src = (c < 64) ? (x0 + (size_t)m * 256 + c * 4)
                              : (x1 + (size_t)m * 256 + (c - 64) * 4);
  const float4 v = *(const float4*)src;
  uint2 pk;
  pk.x = (unsigned)f2bf(v.x) | ((unsigned)f2bf(v.y) << 16);
  pk.y = (unsigned)f2bf(v.z) | ((unsigned)f2bf(v.w) << 16);
  *(uint2*)&A0[(size_t)m * 512 + c * 4] = pk;
}

// Wt[N,K] bf16 <- W[K,N] f32, 32x32 LDS tile transpose.
__global__ void transpose_cast(const float* __restrict__ W, u16* __restrict__ Wt,
                               int K, int N)
{
  __shared__ float tile[32][33];
  const int tx = threadIdx.x & 31;
  const int ty = threadIdx.x >> 5;  // 0..7
  const int k0 = blockIdx.x * 32;
  const int n0 = blockIdx.y * 32;
#pragma unroll
  for (int i = 0; i < 32; i += 8)
    tile[ty + i][tx] = W[(size_t)(k0 + ty + i) * N + n0 + tx];
  __syncthreads();
#pragma unroll
  for (int i = 0; i < 32; i += 8)
    Wt[(size_t)(n0 + ty + i) * K + k0 + tx] = f2bf(tile[tx][ty + i]);
}

extern "C" void kernel_launch(void* const* d_in, const int* in_sizes, int n_in,
                              void* d_out, int out_size, void* d_ws, size_t ws_size,
                              hipStream_t stream)
{
  const float* x0 = (const float*)d_in[0];
  const float* x1 = (const float*)d_in[1];
  const float* t  = (const float*)d_in[2];
  const float* W1 = (const float*)d_in[3];
  const float* b1 = (const float*)d_in[4];
  const float* W2 = (const float*)d_in[5];
  const float* b2 = (const float*)d_in[6];
  const float* W3 = (const float*)d_in[7];
  const float* b3 = (const float*)d_in[8];
  const float* W4 = (const float*)d_in[9];
  const float* b4 = (const float*)d_in[10];

  char* ws = (char*)d_ws;
  const size_t WB1 = (size_t)512 * HDIM * 2;   // 1 MiB
  const size_t WB2 = (size_t)HDIM * HDIM * 2;  // 2 MiB
  const size_t WB4 = (size_t)HDIM * SDIM * 2;  // 0.5 MiB
  u16* Wt1 = (u16*)(ws);
  u16* Wt2 = (u16*)(ws + WB1);
  u16* Wt3 = (u16*)(ws + WB1 + WB2);
  u16* Wt4 = (u16*)(ws + WB1 + 2 * WB2);
  const size_t wmark = WB1 + 2 * WB2 + WB4;    // 5.5 MiB
  char* act = ws + wmark;

  // Stacked activations: Sa, Sb = [2*CB, 1024] bf16 = CB*4096 B each.
  int nc = 1;
  while (nc < 64 && wmark + (size_t)(BATCH / nc) * 8192 > ws_size) nc <<= 1;
  const int CB = BATCH / nc;

  u16* Sa = (u16*)(act);
  u16* Sb = (u16*)(act + (size_t)CB * 4096);
  u16* Zc = Sb;  // alias: Z chunk (CB*1024 B) dead once layer 2 writes Sb

  transpose_cast<<<dim3(16, 32), 256, 0, stream>>>(W1, Wt1, 512, HDIM);
  transpose_cast<<<dim3(32, 32), 256, 0, stream>>>(W2, Wt2, HDIM, HDIM);
  transpose_cast<<<dim3(32, 32), 256, 0, stream>>>(W3, Wt3, HDIM, HDIM);
  transpose_cast<<<dim3(32, 8),  256, 0, stream>>>(W4, Wt4, HDIM, SDIM);

  const float* r1 = W1 + (size_t)512 * HDIM;   // last row of W1
  float* out_xt = (float*)d_out;
  float* out_dt = (float*)d_out + (size_t)BATCH * SDIM;

  for (int c = 0; c < nc; ++c) {
    const size_t mb = (size_t)c * CB;

    prep_z<<<(CB * 128) / 256, 256, 0, stream>>>(x0 + mb * SDIM, x1 + mb * SDIM, Zc);

    { EpiArgs e{}; e.bias = b1; e.r1 = r1; e.t = t + mb; e.out_h = Sa;
      fgemm8<0><<<dim3(HDIM / 256, CB / 256), 512, 0, stream>>>(Zc, Wt1, HDIM, 512, e); }

    { EpiArgs e{}; e.bias = b2; e.out_h = Sb;
      fgemm8<1><<<dim3(HDIM / 256, CB / 128), 512, 0, stream>>>(Sa, Wt2, HDIM, HDIM, e); }

    { EpiArgs e{}; e.bias = b3; e.out_h = Sa;
      fgemm8<1><<<dim3(HDIM / 256, CB / 128), 512, 0, stream>>>(Sb, Wt3, HDIM, HDIM, e); }

    { EpiArgs e{}; e.bias = b4; e.t = t + mb;
      e.x0 = x0 + mb * SDIM; e.x1 = x1 + mb * SDIM;
      e.out_xt = out_xt + mb * SDIM; e.out_dt = out_dt + mb * SDIM;
      fgemm8<2><<<dim3(SDIM / 256, CB / 128), 512, 0, stream>>>(Sa, Wt4, SDIM, HDIM, e); }
  }
}